// Round 3
// baseline (10298.774 us; speedup 1.0000x reference)
//
#include <hip/hip_runtime.h>
#include <cstddef>

#define NCF 10

struct TFKeys { unsigned k[2 * NCF]; };

// Threefry-2x32, 20 rounds (JAX partitionable semantics, verified R1/R2).
__host__ __device__ __forceinline__ void tf2x32(unsigned k0, unsigned k1,
                                                unsigned x0, unsigned x1,
                                                unsigned& o0, unsigned& o1) {
  const unsigned ks2 = k0 ^ k1 ^ 0x1BD11BDAu;
  x0 += k0; x1 += k1;
#define TF_R(r) x0 += x1; x1 = (x1 << (r)) | (x1 >> (32 - (r))); x1 ^= x0;
  TF_R(13) TF_R(15) TF_R(26) TF_R(6)
  x0 += k1;  x1 += ks2 + 1u;
  TF_R(17) TF_R(29) TF_R(16) TF_R(24)
  x0 += ks2; x1 += k0 + 2u;
  TF_R(13) TF_R(15) TF_R(26) TF_R(6)
  x0 += k0;  x1 += k1 + 3u;
  TF_R(17) TF_R(29) TF_R(16) TF_R(24)
  x0 += k1;  x1 += ks2 + 4u;
  TF_R(13) TF_R(15) TF_R(26) TF_R(6)
  x0 += ks2; x1 += k0 + 5u;
#undef TF_R
  o0 = x0; o1 = x1;
}

__device__ __forceinline__ float u01(unsigned bits) {
  return __uint_as_float((bits >> 9) | 0x3f800000u) - 1.0f;
}

// 16 FMAs: acc[0..3] (4 cols) += a.{x,y,z,w} (4 k) * w{0..3}.{col}
#define FMA4(ac, av, w0, w1, w2, w3)                                        \
  ac[0] = fmaf(av.x, w0.x, ac[0]); ac[0] = fmaf(av.y, w1.x, ac[0]);         \
  ac[0] = fmaf(av.z, w2.x, ac[0]); ac[0] = fmaf(av.w, w3.x, ac[0]);         \
  ac[1] = fmaf(av.x, w0.y, ac[1]); ac[1] = fmaf(av.y, w1.y, ac[1]);         \
  ac[1] = fmaf(av.z, w2.y, ac[1]); ac[1] = fmaf(av.w, w3.y, ac[1]);         \
  ac[2] = fmaf(av.x, w0.z, ac[2]); ac[2] = fmaf(av.y, w1.z, ac[2]);         \
  ac[2] = fmaf(av.z, w2.z, ac[2]); ac[2] = fmaf(av.w, w3.z, ac[2]);         \
  ac[3] = fmaf(av.x, w0.w, ac[3]); ac[3] = fmaf(av.y, w1.w, ac[3]);         \
  ac[3] = fmaf(av.z, w2.w, ac[3]); ac[3] = fmaf(av.w, w3.w, ac[3]);

// S=131072. 4096 WGs x 256 threads (4 waves). Wave owns 8 samples end-to-end.
// Weights read from GLOBAL (L1/L2-cached, VMEM pipe) — LDS holds only per-wave
// activations. Zero __syncthreads in the entire kernel.
__global__ __launch_bounds__(256, 3)
void infl_kernel(const float* __restrict__ obs, const float* __restrict__ actions,
                 const float* __restrict__ W1, const float* __restrict__ b1,
                 const float* __restrict__ W2, const float* __restrict__ b2,
                 const float* __restrict__ W3, const float* __restrict__ b3,
                 float* __restrict__ out, TFKeys keys) {
  // 4 waves x 2144 floats = 34.3 KB -> 3-4 WG/CU
  __shared__ __align__(16) float s_scratch[4 * 2144];

  const int t    = threadIdx.x;
  const int wave = t >> 6;
  const int lane = t & 63;
  float* wsc   = &s_scratch[wave * 2144];
  float* s_act = wsc;                 // stride 68 (phase1: obs stride 260)
  float* s_h1  = wsc + 544;           // stride 132
  float* s_h2  = wsc + 544 + 1056;    // stride 68
  const int g_base = blockIdx.x * 32 + wave * 8;

  // ---- stage this wave's obs (8 x 256 -> stride 260), intra-wave only
  {
    const float4* src = (const float4*)(obs + (size_t)g_base * 256);
#pragma unroll
    for (int i = 0; i < 8; ++i) {
      const int q = lane + (i << 6);            // float4 index 0..511
      const int s = q >> 6, c = (q & 63) << 2;
      *(float4*)(wsc + s * 260 + c) = src[q];
    }
  }

  // ---- phase 1: hobs = obs @ W1[0:256,:] + b1
  const int s0 = (lane >> 5) << 2;   // 0 or 4
  const int c0 = (lane & 31) << 2;   // 0..124
  float hobs[4][4];
#pragma unroll
  for (int r = 0; r < 4; ++r)
#pragma unroll
    for (int c = 0; c < 4; ++c) hobs[r][c] = 0.f;

  for (int blk = 0; blk < 4; ++blk) {
    const float* wb = W1 + (size_t)blk * 64 * 128 + c0;
    const int kb = blk << 6;
#pragma unroll
    for (int kc = 0; kc < 16; ++kc) {
      const float* wp = wb + kc * 4 * 128;
      const float4 w0 = *(const float4*)(wp);
      const float4 w1 = *(const float4*)(wp + 128);
      const float4 w2 = *(const float4*)(wp + 256);
      const float4 w3 = *(const float4*)(wp + 384);
#pragma unroll
      for (int r = 0; r < 4; ++r) {
        const float4 a = *(const float4*)(wsc + (s0 + r) * 260 + kb + kc * 4);
        FMA4(hobs[r], a, w0, w1, w2, w3)
      }
    }
  }
  {  // fold b1
    const float4 bv = *(const float4*)(b1 + c0);
#pragma unroll
    for (int r = 0; r < 4; ++r) {
      hobs[r][0] += bv.x; hobs[r][1] += bv.y;
      hobs[r][2] += bv.z; hobs[r][3] += bv.w;
    }
  }

  // L2/L3/epilogue lane map: 2 samples x 4 cols
  const int sg = lane >> 4;            // 0..3
  const int c2 = (lane & 15) << 2;     // 0..60
  const float4 b2v = *(const float4*)(b2 + c2);
  const float4 b3v = *(const float4*)(b3 + c2);

  const float* W1a = W1 + 256 * 128;   // action part, rows 256..319

  float pwith[2][4], pacc[2][4];
#pragma unroll
  for (int r = 0; r < 2; ++r)
#pragma unroll
    for (int c = 0; c < 4; ++c) pacc[r][c] = 0.f;

  // ---- 12 passes, barrier-free
  for (int pass = 0; pass < 12; ++pass) {
    if (pass == 0) {
      const float4* src = (const float4*)(actions + (size_t)g_base * 64);
#pragma unroll
      for (int i = 0; i < 2; ++i) {
        const int q = lane + (i << 6);           // 0..127
        const int s = q >> 4, c = (q & 15) << 2;
        *(float4*)(s_act + s * 68 + c) = src[q];
      }
    } else if (pass >= 2) {
      const unsigned k0 = keys.k[2 * (pass - 2)];
      const unsigned k1 = keys.k[2 * (pass - 2) + 1];
      const int s = lane >> 3, cb = (lane & 7) << 3;
      const unsigned base = (unsigned)(g_base + s) * 64u + (unsigned)cb;
      float v[8];
#pragma unroll
      for (int e = 0; e < 8; ++e) {
        unsigned o0, o1;
        tf2x32(k0, k1, 0u, base + (unsigned)e, o0, o1);
        v[e] = u01(o0 ^ o1);
      }
      *(float4*)(s_act + s * 68 + cb)     = make_float4(v[0], v[1], v[2], v[3]);
      *(float4*)(s_act + s * 68 + cb + 4) = make_float4(v[4], v[5], v[6], v[7]);
    }

    // ---- layer 1: h1 = relu(hobs + act @ W1a)   (pass 1: act == 0)
    if (pass == 1) {
#pragma unroll
      for (int r = 0; r < 4; ++r) {
        float4 hv;
        hv.x = fmaxf(hobs[r][0], 0.f); hv.y = fmaxf(hobs[r][1], 0.f);
        hv.z = fmaxf(hobs[r][2], 0.f); hv.w = fmaxf(hobs[r][3], 0.f);
        *(float4*)(s_h1 + (s0 + r) * 132 + c0) = hv;
      }
    } else {
      float acc[4][4];
#pragma unroll
      for (int r = 0; r < 4; ++r)
#pragma unroll
        for (int c = 0; c < 4; ++c) acc[r][c] = 0.f;
#pragma unroll
      for (int kc = 0; kc < 16; ++kc) {
        const float* wp = W1a + kc * 4 * 128 + c0;
        const float4 w0 = *(const float4*)(wp);
        const float4 w1 = *(const float4*)(wp + 128);
        const float4 w2 = *(const float4*)(wp + 256);
        const float4 w3 = *(const float4*)(wp + 384);
#pragma unroll
        for (int r = 0; r < 4; ++r) {
          const float4 a = *(const float4*)(s_act + (s0 + r) * 68 + kc * 4);
          FMA4(acc[r], a, w0, w1, w2, w3)
        }
      }
#pragma unroll
      for (int r = 0; r < 4; ++r) {
        float4 hv;
        hv.x = fmaxf(hobs[r][0] + acc[r][0], 0.f);
        hv.y = fmaxf(hobs[r][1] + acc[r][1], 0.f);
        hv.z = fmaxf(hobs[r][2] + acc[r][2], 0.f);
        hv.w = fmaxf(hobs[r][3] + acc[r][3], 0.f);
        *(float4*)(s_h1 + (s0 + r) * 132 + c0) = hv;
      }
    }

    // ---- layer 2: h2 = relu(h1 @ W2 + b2)
    float acc2[2][4];
#pragma unroll
    for (int r = 0; r < 2; ++r)
#pragma unroll
      for (int c = 0; c < 4; ++c) acc2[r][c] = 0.f;
#pragma unroll
    for (int kc = 0; kc < 32; ++kc) {
      const float* wp = W2 + kc * 4 * 64 + c2;
      const float4 w0 = *(const float4*)(wp);
      const float4 w1 = *(const float4*)(wp + 64);
      const float4 w2v = *(const float4*)(wp + 128);
      const float4 w3 = *(const float4*)(wp + 192);
      const float4 a0 = *(const float4*)(s_h1 + (2 * sg + 0) * 132 + kc * 4);
      const float4 a1 = *(const float4*)(s_h1 + (2 * sg + 1) * 132 + kc * 4);
      FMA4(acc2[0], a0, w0, w1, w2v, w3)
      FMA4(acc2[1], a1, w0, w1, w2v, w3)
    }
#pragma unroll
    for (int r = 0; r < 2; ++r) {
      float4 hv;
      hv.x = fmaxf(acc2[r][0] + b2v.x, 0.f);
      hv.y = fmaxf(acc2[r][1] + b2v.y, 0.f);
      hv.z = fmaxf(acc2[r][2] + b2v.z, 0.f);
      hv.w = fmaxf(acc2[r][3] + b2v.w, 0.f);
      *(float4*)(s_h2 + (2 * sg + r) * 68 + c2) = hv;
    }

    // ---- layer 3: p = h2 @ W3 + b3
    float acc3[2][4];
#pragma unroll
    for (int r = 0; r < 2; ++r)
#pragma unroll
      for (int c = 0; c < 4; ++c) acc3[r][c] = 0.f;
#pragma unroll
    for (int kc = 0; kc < 16; ++kc) {
      const float* wp = W3 + kc * 4 * 64 + c2;
      const float4 w0 = *(const float4*)(wp);
      const float4 w1 = *(const float4*)(wp + 64);
      const float4 w2v = *(const float4*)(wp + 128);
      const float4 w3 = *(const float4*)(wp + 192);
      const float4 a0 = *(const float4*)(s_h2 + (2 * sg + 0) * 68 + kc * 4);
      const float4 a1 = *(const float4*)(s_h2 + (2 * sg + 1) * 68 + kc * 4);
      FMA4(acc3[0], a0, w0, w1, w2v, w3)
      FMA4(acc3[1], a1, w0, w1, w2v, w3)
    }
    if (pass == 0) {
#pragma unroll
      for (int r = 0; r < 2; ++r) {
        pwith[r][0] = acc3[r][0] + b3v.x; pwith[r][1] = acc3[r][1] + b3v.y;
        pwith[r][2] = acc3[r][2] + b3v.z; pwith[r][3] = acc3[r][3] + b3v.w;
      }
    } else {
#pragma unroll
      for (int r = 0; r < 2; ++r) {
        pacc[r][0] += acc3[r][0] + b3v.x; pacc[r][1] += acc3[r][1] + b3v.y;
        pacc[r][2] += acc3[r][2] + b3v.z; pacc[r][3] += acc3[r][3] + b3v.w;
      }
    }
  }

  // ---- epilogue: influence = mean_a q*(logq-logp), 16-lane shfl reductions
  const float inv11 = 1.0f / 11.0f;
#pragma unroll
  for (int r = 0; r < 2; ++r) {
    float pw[4], pa[4];
#pragma unroll
    for (int c = 0; c < 4; ++c) { pw[c] = pwith[r][c]; pa[c] = pacc[r][c] * inv11; }
    float mw = fmaxf(fmaxf(pw[0], pw[1]), fmaxf(pw[2], pw[3]));
    float ma = fmaxf(fmaxf(pa[0], pa[1]), fmaxf(pa[2], pa[3]));
#pragma unroll
    for (int off = 1; off < 16; off <<= 1) {
      mw = fmaxf(mw, __shfl_xor(mw, off, 64));
      ma = fmaxf(ma, __shfl_xor(ma, off, 64));
    }
    float sw = 0.f, sa = 0.f;
#pragma unroll
    for (int c = 0; c < 4; ++c) { sw += expf(pw[c] - mw); sa += expf(pa[c] - ma); }
#pragma unroll
    for (int off = 1; off < 16; off <<= 1) {
      sw += __shfl_xor(sw, off, 64);
      sa += __shfl_xor(sa, off, 64);
    }
    const float lzw = logf(sw), lza = logf(sa);
    float contrib = 0.f;
#pragma unroll
    for (int c = 0; c < 4; ++c) {
      const float lq = pa[c] - ma - lza;
      const float lp = pw[c] - mw - lzw;
      contrib += expf(lq) * (lq - lp);
    }
#pragma unroll
    for (int off = 1; off < 16; off <<= 1)
      contrib += __shfl_xor(contrib, off, 64);
    if ((lane & 15) == 0) out[g_base + 2 * sg + r] = contrib * (1.0f / 64.0f);
  }
}

extern "C" void kernel_launch(void* const* d_in, const int* in_sizes, int n_in,
                              void* d_out, int out_size, void* d_ws, size_t ws_size,
                              hipStream_t stream) {
  (void)in_sizes; (void)n_in; (void)d_ws; (void)ws_size; (void)out_size;
  const float* obs     = (const float*)d_in[0];
  const float* actions = (const float*)d_in[1];
  const float* W1      = (const float*)d_in[2];
  const float* b1      = (const float*)d_in[3];
  const float* W2      = (const float*)d_in[4];
  const float* b2      = (const float*)d_in[5];
  const float* W3      = (const float*)d_in[6];
  const float* b3      = (const float*)d_in[7];

  TFKeys keys;
  for (unsigned j = 0; j < NCF; ++j) {
    unsigned o0, o1;
    tf2x32(0u, 42u, 0u, j, o0, o1);
    keys.k[2 * j]     = o0;
    keys.k[2 * j + 1] = o1;
  }

  hipLaunchKernelGGL(infl_kernel, dim3(4096), dim3(256), 0, stream,
                     obs, actions, W1, b1, W2, b2, W3, b3, (float*)d_out, keys);
}

// Round 4
// 1339.605 us; speedup vs baseline: 7.6879x; 7.6879x over previous
//
#include <hip/hip_runtime.h>
#include <cstddef>

#define NCF 10

struct TFKeys { unsigned k[2 * NCF]; };

// Threefry-2x32, 20 rounds (JAX partitionable semantics, verified R1/R2).
__host__ __device__ __forceinline__ void tf2x32(unsigned k0, unsigned k1,
                                                unsigned x0, unsigned x1,
                                                unsigned& o0, unsigned& o1) {
  const unsigned ks2 = k0 ^ k1 ^ 0x1BD11BDAu;
  x0 += k0; x1 += k1;
#define TF_R(r) x0 += x1; x1 = (x1 << (r)) | (x1 >> (32 - (r))); x1 ^= x0;
  TF_R(13) TF_R(15) TF_R(26) TF_R(6)
  x0 += k1;  x1 += ks2 + 1u;
  TF_R(17) TF_R(29) TF_R(16) TF_R(24)
  x0 += ks2; x1 += k0 + 2u;
  TF_R(13) TF_R(15) TF_R(26) TF_R(6)
  x0 += k0;  x1 += k1 + 3u;
  TF_R(17) TF_R(29) TF_R(16) TF_R(24)
  x0 += k1;  x1 += ks2 + 4u;
  TF_R(13) TF_R(15) TF_R(26) TF_R(6)
  x0 += ks2; x1 += k0 + 5u;
#undef TF_R
  o0 = x0; o1 = x1;
}

__device__ __forceinline__ float u01(unsigned bits) {
  return __uint_as_float((bits >> 9) | 0x3f800000u) - 1.0f;
}

// 16 FMAs: acc[0..3] (4 cols) += a.{x,y,z,w} (4 k) * w{0..3}.{col}
#define FMA4(ac, av, w0, w1, w2, w3)                                        \
  ac[0] = fmaf(av.x, w0.x, ac[0]); ac[0] = fmaf(av.y, w1.x, ac[0]);         \
  ac[0] = fmaf(av.z, w2.x, ac[0]); ac[0] = fmaf(av.w, w3.x, ac[0]);         \
  ac[1] = fmaf(av.x, w0.y, ac[1]); ac[1] = fmaf(av.y, w1.y, ac[1]);         \
  ac[1] = fmaf(av.z, w2.y, ac[1]); ac[1] = fmaf(av.w, w3.y, ac[1]);         \
  ac[2] = fmaf(av.x, w0.z, ac[2]); ac[2] = fmaf(av.y, w1.z, ac[2]);         \
  ac[2] = fmaf(av.z, w2.z, ac[2]); ac[2] = fmaf(av.w, w3.z, ac[2]);         \
  ac[3] = fmaf(av.x, w0.w, ac[3]); ac[3] = fmaf(av.y, w1.w, ac[3]);         \
  ac[3] = fmaf(av.z, w2.w, ac[3]); ac[3] = fmaf(av.w, w3.w, ac[3]);

// S=131072. 1024 WGs x 512 threads (8 waves). Wave owns 16 samples end-to-end.
// Weights from GLOBAL (L1/L2, VMEM pipe) with register-pressure-controlled
// loops (R3 post-mortem: full unroll spilled -> 20 GB HBM thrash).
// LDS = per-wave activation scratch only (17.2 KB/wave). Zero barriers.
__global__ __launch_bounds__(512, 2)
void infl_kernel(const float* __restrict__ obs, const float* __restrict__ actions,
                 const float* __restrict__ W1, const float* __restrict__ b1,
                 const float* __restrict__ W2, const float* __restrict__ b2,
                 const float* __restrict__ W3, const float* __restrict__ b3,
                 float* __restrict__ out, TFKeys keys) {
  // 8 waves x 4288 floats = 137,216 B -> 1 WG/CU, 8 waves/CU (2/SIMD)
  __shared__ __align__(16) float s_scratch[8 * 4288];

  const int t    = threadIdx.x;
  const int wave = t >> 6;
  const int lane = t & 63;
  float* wsc   = &s_scratch[wave * 4288];
  float* s_act = wsc;                  // 16 x stride 68  (phase1: obs 16 x 260)
  float* s_h1  = wsc + 1088;           // 16 x stride 132
  float* s_h2  = wsc + 1088 + 2112;    // 16 x stride 68
  const int g_base = (blockIdx.x * 8 + wave) * 16;   // wave's first sample

  // ---- stage this wave's obs (16 x 256 -> stride 260), intra-wave only
  {
    const float4* src = (const float4*)(obs + (size_t)g_base * 256);
#pragma unroll
    for (int i = 0; i < 16; ++i) {
      const int q = lane + (i << 6);            // float4 index 0..1023
      const int s = q >> 6, c = (q & 63) << 2;
      *(float4*)(wsc + s * 260 + c) = src[q];
    }
  }

  // ---- phase 1: hobs = obs @ W1[0:256,:] + b1   (16 samples, regs)
  const int oct = lane >> 5;           // 0/1 -> samples oct*8 .. oct*8+7
  const int c0  = (lane & 31) << 2;    // h1 col group 0..124
  float hobs[8][4];
#pragma unroll
  for (int r = 0; r < 8; ++r)
#pragma unroll
    for (int c = 0; c < 4; ++c) hobs[r][c] = 0.f;

  for (int blk = 0; blk < 4; ++blk) {
    const float* wb = W1 + (size_t)blk * 64 * 128 + c0;
    const int kb = blk << 6;
#pragma unroll 2
    for (int kc = 0; kc < 16; ++kc) {
      const float* wp = wb + kc * 512;
      const float4 w0 = *(const float4*)(wp);
      const float4 w1 = *(const float4*)(wp + 128);
      const float4 w2 = *(const float4*)(wp + 256);
      const float4 w3 = *(const float4*)(wp + 384);
#pragma unroll
      for (int r = 0; r < 8; ++r) {
        const float4 a = *(const float4*)(wsc + (oct * 8 + r) * 260 + kb + kc * 4);
        FMA4(hobs[r], a, w0, w1, w2, w3)
      }
    }
  }
  {  // fold b1
    const float4 bv = *(const float4*)(b1 + c0);
#pragma unroll
    for (int r = 0; r < 8; ++r) {
      hobs[r][0] += bv.x; hobs[r][1] += bv.y;
      hobs[r][2] += bv.z; hobs[r][3] += bv.w;
    }
  }

  // L2/L3/epilogue lane map: 4 samples x 4 cols
  const int sg = lane >> 4;            // 0..3 -> samples 4sg..4sg+3
  const int c2 = (lane & 15) << 2;     // 0..60
  const float4 b2v = *(const float4*)(b2 + c2);
  const float4 b3v = *(const float4*)(b3 + c2);

  const float* W1a = W1 + 256 * 128;   // action rows 256..319

  float pwith[4][4], pacc[4][4];
#pragma unroll
  for (int r = 0; r < 4; ++r)
#pragma unroll
    for (int c = 0; c < 4; ++c) pacc[r][c] = 0.f;

  // ---- 12 passes, barrier-free
  for (int pass = 0; pass < 12; ++pass) {
    if (pass == 0) {
      const float4* src = (const float4*)(actions + (size_t)g_base * 64);
#pragma unroll
      for (int i = 0; i < 4; ++i) {
        const int q = lane + (i << 6);           // 0..255
        const int s = q >> 4, c = (q & 15) << 2;
        *(float4*)(s_act + s * 68 + c) = src[q];
      }
    } else if (pass >= 2) {
      const unsigned k0 = keys.k[2 * (pass - 2)];
      const unsigned k1 = keys.k[2 * (pass - 2) + 1];
      const int s = lane >> 2, cb = (lane & 3) << 4;   // 16 elems/lane
      const unsigned base = (unsigned)(g_base + s) * 64u + (unsigned)cb;
      float* dst = s_act + s * 68 + cb;
#pragma unroll
      for (int q4 = 0; q4 < 4; ++q4) {
        float v[4];
#pragma unroll
        for (int e = 0; e < 4; ++e) {
          unsigned o0, o1;
          tf2x32(k0, k1, 0u, base + (unsigned)(q4 * 4 + e), o0, o1);
          v[e] = u01(o0 ^ o1);
        }
        *(float4*)(dst + 4 * q4) = make_float4(v[0], v[1], v[2], v[3]);
      }
    }

    // ---- layer 1: h1 = relu(hobs + act @ W1a)   (pass 1: act == 0)
    if (pass == 1) {
#pragma unroll
      for (int r = 0; r < 8; ++r) {
        float4 hv;
        hv.x = fmaxf(hobs[r][0], 0.f); hv.y = fmaxf(hobs[r][1], 0.f);
        hv.z = fmaxf(hobs[r][2], 0.f); hv.w = fmaxf(hobs[r][3], 0.f);
        *(float4*)(s_h1 + (oct * 8 + r) * 132 + c0) = hv;
      }
    } else {
      float acc[8][4];
#pragma unroll
      for (int r = 0; r < 8; ++r)
#pragma unroll
        for (int c = 0; c < 4; ++c) acc[r][c] = 0.f;
#pragma unroll 2
      for (int kc = 0; kc < 16; ++kc) {
        const float* wp = W1a + kc * 512 + c0;
        const float4 w0 = *(const float4*)(wp);
        const float4 w1 = *(const float4*)(wp + 128);
        const float4 w2 = *(const float4*)(wp + 256);
        const float4 w3 = *(const float4*)(wp + 384);
#pragma unroll
        for (int r = 0; r < 8; ++r) {
          const float4 a = *(const float4*)(s_act + (oct * 8 + r) * 68 + kc * 4);
          FMA4(acc[r], a, w0, w1, w2, w3)
        }
      }
#pragma unroll
      for (int r = 0; r < 8; ++r) {
        float4 hv;
        hv.x = fmaxf(hobs[r][0] + acc[r][0], 0.f);
        hv.y = fmaxf(hobs[r][1] + acc[r][1], 0.f);
        hv.z = fmaxf(hobs[r][2] + acc[r][2], 0.f);
        hv.w = fmaxf(hobs[r][3] + acc[r][3], 0.f);
        *(float4*)(s_h1 + (oct * 8 + r) * 132 + c0) = hv;
      }
    }

    // ---- layer 2: h2 = relu(h1 @ W2 + b2)
    float acc2[4][4];
#pragma unroll
    for (int r = 0; r < 4; ++r)
#pragma unroll
      for (int c = 0; c < 4; ++c) acc2[r][c] = 0.f;
#pragma unroll 4
    for (int kc = 0; kc < 32; ++kc) {
      const float* wp = W2 + kc * 256 + c2;
      const float4 w0 = *(const float4*)(wp);
      const float4 w1 = *(const float4*)(wp + 64);
      const float4 w2v = *(const float4*)(wp + 128);
      const float4 w3 = *(const float4*)(wp + 192);
#pragma unroll
      for (int r = 0; r < 4; ++r) {
        const float4 a = *(const float4*)(s_h1 + (4 * sg + r) * 132 + kc * 4);
        FMA4(acc2[r], a, w0, w1, w2v, w3)
      }
    }
#pragma unroll
    for (int r = 0; r < 4; ++r) {
      float4 hv;
      hv.x = fmaxf(acc2[r][0] + b2v.x, 0.f);
      hv.y = fmaxf(acc2[r][1] + b2v.y, 0.f);
      hv.z = fmaxf(acc2[r][2] + b2v.z, 0.f);
      hv.w = fmaxf(acc2[r][3] + b2v.w, 0.f);
      *(float4*)(s_h2 + (4 * sg + r) * 68 + c2) = hv;
    }

    // ---- layer 3: p = h2 @ W3 + b3
    float acc3[4][4];
#pragma unroll
    for (int r = 0; r < 4; ++r)
#pragma unroll
      for (int c = 0; c < 4; ++c) acc3[r][c] = 0.f;
#pragma unroll 4
    for (int kc = 0; kc < 16; ++kc) {
      const float* wp = W3 + kc * 256 + c2;
      const float4 w0 = *(const float4*)(wp);
      const float4 w1 = *(const float4*)(wp + 64);
      const float4 w2v = *(const float4*)(wp + 128);
      const float4 w3 = *(const float4*)(wp + 192);
#pragma unroll
      for (int r = 0; r < 4; ++r) {
        const float4 a = *(const float4*)(s_h2 + (4 * sg + r) * 68 + kc * 4);
        FMA4(acc3[r], a, w0, w1, w2v, w3)
      }
    }
    if (pass == 0) {
#pragma unroll
      for (int r = 0; r < 4; ++r) {
        pwith[r][0] = acc3[r][0] + b3v.x; pwith[r][1] = acc3[r][1] + b3v.y;
        pwith[r][2] = acc3[r][2] + b3v.z; pwith[r][3] = acc3[r][3] + b3v.w;
      }
    } else {
#pragma unroll
      for (int r = 0; r < 4; ++r) {
        pacc[r][0] += acc3[r][0] + b3v.x; pacc[r][1] += acc3[r][1] + b3v.y;
        pacc[r][2] += acc3[r][2] + b3v.z; pacc[r][3] += acc3[r][3] + b3v.w;
      }
    }
  }

  // ---- epilogue: influence = mean_a q*(logq-logp), 16-lane shfl reductions
  const float inv11 = 1.0f / 11.0f;
#pragma unroll
  for (int r = 0; r < 4; ++r) {
    float pw[4], pa[4];
#pragma unroll
    for (int c = 0; c < 4; ++c) { pw[c] = pwith[r][c]; pa[c] = pacc[r][c] * inv11; }
    float mw = fmaxf(fmaxf(pw[0], pw[1]), fmaxf(pw[2], pw[3]));
    float ma = fmaxf(fmaxf(pa[0], pa[1]), fmaxf(pa[2], pa[3]));
#pragma unroll
    for (int off = 1; off < 16; off <<= 1) {
      mw = fmaxf(mw, __shfl_xor(mw, off, 64));
      ma = fmaxf(ma, __shfl_xor(ma, off, 64));
    }
    float sw = 0.f, sa = 0.f;
#pragma unroll
    for (int c = 0; c < 4; ++c) { sw += expf(pw[c] - mw); sa += expf(pa[c] - ma); }
#pragma unroll
    for (int off = 1; off < 16; off <<= 1) {
      sw += __shfl_xor(sw, off, 64);
      sa += __shfl_xor(sa, off, 64);
    }
    const float lzw = logf(sw), lza = logf(sa);
    float contrib = 0.f;
#pragma unroll
    for (int c = 0; c < 4; ++c) {
      const float lq = pa[c] - ma - lza;
      const float lp = pw[c] - mw - lzw;
      contrib += expf(lq) * (lq - lp);
    }
#pragma unroll
    for (int off = 1; off < 16; off <<= 1)
      contrib += __shfl_xor(contrib, off, 64);
    if ((lane & 15) == 0) out[g_base + 4 * sg + r] = contrib * (1.0f / 64.0f);
  }
}

extern "C" void kernel_launch(void* const* d_in, const int* in_sizes, int n_in,
                              void* d_out, int out_size, void* d_ws, size_t ws_size,
                              hipStream_t stream) {
  (void)in_sizes; (void)n_in; (void)d_ws; (void)ws_size; (void)out_size;
  const float* obs     = (const float*)d_in[0];
  const float* actions = (const float*)d_in[1];
  const float* W1      = (const float*)d_in[2];
  const float* b1      = (const float*)d_in[3];
  const float* W2      = (const float*)d_in[4];
  const float* b2      = (const float*)d_in[5];
  const float* W3      = (const float*)d_in[6];
  const float* b3      = (const float*)d_in[7];

  TFKeys keys;
  for (unsigned j = 0; j < NCF; ++j) {
    unsigned o0, o1;
    tf2x32(0u, 42u, 0u, j, o0, o1);
    keys.k[2 * j]     = o0;
    keys.k[2 * j + 1] = o1;
  }

  hipLaunchKernelGGL(infl_kernel, dim3(1024), dim3(512), 0, stream,
                     obs, actions, W1, b1, W2, b2, W3, b3, (float*)d_out, keys);
}